// Round 4
// baseline (264.940 us; speedup 1.0000x reference)
//
#include <hip/hip_runtime.h>
#include <hip/hip_bf16.h>

#define NDIM 256
#define NROT 32640          // C(256,2)
#define NSEG 64
#define SEGLEN 510          // 64 * 510 == 32640 exactly
#define MATE (NDIM * NDIM)  // elements per matrix

typedef __bf16 bf16x4_t __attribute__((ext_vector_type(4)));
typedef __bf16 bf16x8_t __attribute__((ext_vector_type(8)));
typedef float f32x4_t __attribute__((ext_vector_type(4)));

// ---------------------------------------------------------------------------
// K1: precompute cos/sin for all rotations
// ---------------------------------------------------------------------------
__global__ void k_sincos(const float* __restrict__ rots, float2* __restrict__ cs) {
    int k = blockIdx.x * 256 + threadIdx.x;
    if (k < NROT) {
        float th = rots[k];
        float s, c;
        sincosf(th, &s, &c);
        cs[k] = make_float2(c, s);
    }
}

// ---------------------------------------------------------------------------
// K2: build 64 segment products P_s (510 rotations each) applied to I, fp32.
// Lexicographic combinations(256,2): within a run (fixed i), row i stays in a
// register; each j-row touched once.  Latency attack vs R3 (41.6us, VGPR=24 ->
// compiler killed the pipeline):
//   - __launch_bounds__(64,1): unlock VGPRs so the 2-deep batch stays resident
//   - cs staged to LDS once per block (4KB): no HBM latency in the chain
//   - peeled last batch -> unconditional prefetch in the steady-state loop
// Storage: even seg -> TRANSPOSED (RHS-ready [c][k]); odd seg -> plain.
// ---------------------------------------------------------------------------
__global__ __launch_bounds__(64, 1) void k_build(const float2* __restrict__ cs,
                                                 float* __restrict__ leaves) {
    __shared__ float tile[NDIM * 64];   // 64 KiB: 256 rows x 64 cols
    __shared__ float2 csl[SEGLEN + 8];
    const int t = threadIdx.x;          // 0..63
    const int seg = blockIdx.x >> 2;
    const int cg = blockIdx.x & 3;
    const int col = cg * 64 + t;

    // stage this segment's (c,s) table into LDS (coalesced float2 reads;
    // global cs buffer is padded so the +8 overfetch stays in-bounds)
    const float2* csg = cs + (size_t)seg * SEGLEN;
    for (int u = t; u < SEGLEN + 8; u += 64) csl[u] = csg[u];

    for (int r = 0; r < NDIM; r++) tile[r * 64 + t] = (r == col) ? 1.0f : 0.0f;
    // single wave: LDS ops execute in order, no barrier needed

    int k = 0;
    const int kg0 = seg * SEGLEN;
    int i = 0, cum = 0;
    while (cum + (NDIM - 1 - i) <= kg0) { cum += NDIM - 1 - i; i++; }
    int j = i + 1 + (kg0 - cum);

    while (k < SEGLEN) {
        float ri = tile[i * 64 + t];
        const int len = min(NDIM - j, SEGLEN - k);
        const int jend = j + len;
        const int nb = len >> 3;

        if (nb > 0) {
            float2 cv[8]; float rj[8];
            #pragma unroll
            for (int u = 0; u < 8; u++) cv[u] = csl[k + u];
            #pragma unroll
            for (int u = 0; u < 8; u++) rj[u] = tile[(j + u) * 64 + t];
            for (int b = 0; b < nb - 1; b++) {
                float2 cvn[8]; float rjn[8];
                #pragma unroll
                for (int u = 0; u < 8; u++) cvn[u] = csl[k + 8 + u];
                #pragma unroll
                for (int u = 0; u < 8; u++) rjn[u] = tile[(j + 8 + u) * 64 + t];
                #pragma unroll
                for (int u = 0; u < 8; u++) {
                    float nri = fmaf(cv[u].x, ri, -(cv[u].y * rj[u]));
                    rj[u]     = fmaf(cv[u].y, ri,  cv[u].x * rj[u]);
                    ri = nri;
                }
                #pragma unroll
                for (int u = 0; u < 8; u++) tile[(j + u) * 64 + t] = rj[u];
                #pragma unroll
                for (int u = 0; u < 8; u++) { cv[u] = cvn[u]; rj[u] = rjn[u]; }
                j += 8; k += 8;
            }
            #pragma unroll
            for (int u = 0; u < 8; u++) {
                float nri = fmaf(cv[u].x, ri, -(cv[u].y * rj[u]));
                rj[u]     = fmaf(cv[u].y, ri,  cv[u].x * rj[u]);
                ri = nri;
            }
            #pragma unroll
            for (int u = 0; u < 8; u++) tile[(j + u) * 64 + t] = rj[u];
            j += 8; k += 8;
        }
        for (; j < jend; j++, k++) {
            float2 cv = csl[k];
            float rj = tile[j * 64 + t];
            float nri = fmaf(cv.x, ri, -(cv.y * rj));
            tile[j * 64 + t] = fmaf(cv.y, ri, cv.x * rj);
            ri = nri;
        }
        tile[i * 64 + t] = ri;
        if (j == NDIM) { i++; j = i + 1; }
    }

    float* dst = leaves + (size_t)seg * MATE;
    if (seg & 1) {
        for (int r = 0; r < NDIM; r++)
            dst[r * NDIM + col] = tile[r * 64 + t];
    } else {
        for (int r0 = 0; r0 < NDIM; r0 += 4) {
            f32x4_t v = {tile[(r0 + 0) * 64 + t], tile[(r0 + 1) * 64 + t],
                         tile[(r0 + 2) * 64 + t], tile[(r0 + 3) * 64 + t]};
            *(f32x4_t*)&dst[(size_t)col * NDIM + r0] = v;
        }
    }
}

// ---------------------------------------------------------------------------
// K3: tree combine, SPLIT-PRECISION bf16 MFMA on fp32 storage.
// node[p] = child[2p+1] @ child[2p];  C ~= Bhi@Ahi + Bhi@Alo + Blo@Ahi
// child[2p] transposed ([c][k]), child[2p+1] plain ([r][k]); output fp32,
// transposed if (!final && p even) else plain.
// ---------------------------------------------------------------------------
#define LDB 40
__global__ __launch_bounds__(256) void k_combine(const float* __restrict__ src,
                                                 float* __restrict__ dst,
                                                 int finalLevel) {
    const int p = blockIdx.x >> 2;
    const int quad = blockIdx.x & 3;
    const int rb = (quad >> 1) * 128;
    const int cb = (quad & 1) * 128;
    const float* A = src + (size_t)(2 * p) * MATE;       // transposed child (RHS)
    const float* B = src + (size_t)(2 * p + 1) * MATE;   // plain child (LHS)
    float* C = dst + (size_t)p * MATE;
    const bool storeT = (!finalLevel) && ((p & 1) == 0);
    const int t = threadIdx.x;
    const int wid = t >> 6, lane = t & 63;
    const int wro = (wid >> 1) * 64, wco = (wid & 1) * 64;
    const int lrow = lane & 15, kg = lane >> 4;

    __shared__ __bf16 Bhi[128 * LDB];
    __shared__ __bf16 Blo[128 * LDB];
    __shared__ __bf16 Ahi[128 * LDB];
    __shared__ __bf16 Alo[128 * LDB];

    f32x4_t acc[4][4] = {};

    for (int kc = 0; kc < NDIM; kc += 32) {
        __syncthreads();
        #pragma unroll
        for (int qq = 0; qq < 4; qq++) {
            int fi = t + qq * 256;
            int row = fi >> 3, sg = fi & 7;
            f32x4_t vb = *(const f32x4_t*)&B[(size_t)(rb + row) * NDIM + kc + sg * 4];
            f32x4_t va = *(const f32x4_t*)&A[(size_t)(cb + row) * NDIM + kc + sg * 4];
            bf16x4_t bh = {(__bf16)vb.x, (__bf16)vb.y, (__bf16)vb.z, (__bf16)vb.w};
            bf16x4_t ah = {(__bf16)va.x, (__bf16)va.y, (__bf16)va.z, (__bf16)va.w};
            bf16x4_t bl = {(__bf16)(vb.x - (float)bh[0]), (__bf16)(vb.y - (float)bh[1]),
                           (__bf16)(vb.z - (float)bh[2]), (__bf16)(vb.w - (float)bh[3])};
            bf16x4_t al = {(__bf16)(va.x - (float)ah[0]), (__bf16)(va.y - (float)ah[1]),
                           (__bf16)(va.z - (float)ah[2]), (__bf16)(va.w - (float)ah[3])};
            *(bf16x4_t*)&Bhi[row * LDB + sg * 4] = bh;
            *(bf16x4_t*)&Blo[row * LDB + sg * 4] = bl;
            *(bf16x4_t*)&Ahi[row * LDB + sg * 4] = ah;
            *(bf16x4_t*)&Alo[row * LDB + sg * 4] = al;
        }
        __syncthreads();

        bf16x8_t afh[4], afl[4], bfh[4], bfl[4];
        #pragma unroll
        for (int mt = 0; mt < 4; mt++) {
            afh[mt] = *(const bf16x8_t*)&Bhi[(wro + mt * 16 + lrow) * LDB + kg * 8];
            afl[mt] = *(const bf16x8_t*)&Blo[(wro + mt * 16 + lrow) * LDB + kg * 8];
        }
        #pragma unroll
        for (int nt = 0; nt < 4; nt++) {
            bfh[nt] = *(const bf16x8_t*)&Ahi[(wco + nt * 16 + lrow) * LDB + kg * 8];
            bfl[nt] = *(const bf16x8_t*)&Alo[(wco + nt * 16 + lrow) * LDB + kg * 8];
        }
        #pragma unroll
        for (int mt = 0; mt < 4; mt++)
            #pragma unroll
            for (int nt = 0; nt < 4; nt++) {
                acc[mt][nt] = __builtin_amdgcn_mfma_f32_16x16x32_bf16(afh[mt], bfh[nt], acc[mt][nt], 0, 0, 0);
                acc[mt][nt] = __builtin_amdgcn_mfma_f32_16x16x32_bf16(afh[mt], bfl[nt], acc[mt][nt], 0, 0, 0);
                acc[mt][nt] = __builtin_amdgcn_mfma_f32_16x16x32_bf16(afl[mt], bfh[nt], acc[mt][nt], 0, 0, 0);
            }
    }

    if (storeT) {
        #pragma unroll
        for (int mt = 0; mt < 4; mt++)
            #pragma unroll
            for (int nt = 0; nt < 4; nt++) {
                int gr = rb + wro + mt * 16 + kg * 4;
                int gc = cb + wco + nt * 16 + lrow;
                *(f32x4_t*)&C[(size_t)gc * NDIM + gr] = acc[mt][nt];
            }
    } else {
        #pragma unroll
        for (int mt = 0; mt < 4; mt++)
            #pragma unroll
            for (int nt = 0; nt < 4; nt++)
                #pragma unroll
                for (int r = 0; r < 4; r++)
                    C[(size_t)(rb + wro + mt * 16 + kg * 4 + r) * NDIM
                      + cb + wco + nt * 16 + lrow] = acc[mt][nt][r];
    }
}

// ---------------------------------------------------------------------------
// K4: Y[b][c] = sum_k X[b][k] * M[c][k]; M fp32 row-major (root), converted
// to bf16 during staging. BM=BN=128, BK=32, 4 waves 2x2, 3 blocks/CU.
// ---------------------------------------------------------------------------
#define LD 40
__global__ __launch_bounds__(256, 3) void k_gemm(const float* __restrict__ X,
                                                 const float* __restrict__ Mmat,
                                                 float* __restrict__ Y) {
    __shared__ __bf16 As[128 * LD];
    __shared__ __bf16 Bs[128 * LD];
    const int bx = blockIdx.x;
    const int xcd = bx & 7;
    const int q = bx >> 3;
    const int bn = (q & 1) * 128;
    const int bm = (xcd + (q >> 1) * 8) * 128;
    const int t = threadIdx.x;
    const int wid = t >> 6;
    const int lane = t & 63;
    const int wr = (wid >> 1) * 64;
    const int wc = (wid & 1) * 64;
    const int lrow = lane & 15;
    const int kg = lane >> 4;

    f32x4_t acc[4][4] = {};

    for (int kc = 0; kc < 256; kc += 32) {
        __syncthreads();
        #pragma unroll
        for (int qq = 0; qq < 4; qq++) {
            int fi = t + qq * 256;
            int row = fi >> 3, sg = fi & 7;
            f32x4_t v = *(const f32x4_t*)&X[(size_t)(bm + row) * 256 + kc + sg * 4];
            bf16x4_t h = {(__bf16)v.x, (__bf16)v.y, (__bf16)v.z, (__bf16)v.w};
            *(bf16x4_t*)&As[row * LD + sg * 4] = h;
        }
        #pragma unroll
        for (int qq = 0; qq < 4; qq++) {
            int fi = t + qq * 256;
            int row = fi >> 3, sg = fi & 7;
            f32x4_t v = *(const f32x4_t*)&Mmat[(size_t)(bn + row) * 256 + kc + sg * 4];
            bf16x4_t h = {(__bf16)v.x, (__bf16)v.y, (__bf16)v.z, (__bf16)v.w};
            *(bf16x4_t*)&Bs[row * LD + sg * 4] = h;
        }
        __syncthreads();

        bf16x8_t af[4], bfr[4];
        #pragma unroll
        for (int mt = 0; mt < 4; mt++)
            af[mt] = *(const bf16x8_t*)&As[(wr + mt * 16 + lrow) * LD + kg * 8];
        #pragma unroll
        for (int nt = 0; nt < 4; nt++)
            bfr[nt] = *(const bf16x8_t*)&Bs[(wc + nt * 16 + lrow) * LD + kg * 8];
        #pragma unroll
        for (int mt = 0; mt < 4; mt++)
            #pragma unroll
            for (int nt = 0; nt < 4; nt++)
                acc[mt][nt] = __builtin_amdgcn_mfma_f32_16x16x32_bf16(af[mt], bfr[nt], acc[mt][nt], 0, 0, 0);
    }

    const int ocol = bn + wc + lrow;
    const int orow = bm + wr + kg * 4;
    #pragma unroll
    for (int mt = 0; mt < 4; mt++)
        #pragma unroll
        for (int nt = 0; nt < 4; nt++)
            #pragma unroll
            for (int r = 0; r < 4; r++)
                Y[(size_t)(orow + mt * 16 + r) * 256 + ocol + nt * 16] = acc[mt][nt][r];
}

// ---------------------------------------------------------------------------
// workspace (bytes):
//   [0, 256K)      cs (float2 x 32640, + >=8 entries pad inside the 256K)
//   B0: 64 fp32 mats (16 MB) ; B1: 32 fp32 mats (8 MB)  -> total 24.25 MB
// tree: B0(64 leaves) ->B1(32) ->B0(16) ->B1(8) ->B0(4) ->B1(2) ->B0(1=root)
// ---------------------------------------------------------------------------
extern "C" void kernel_launch(void* const* d_in, const int* in_sizes, int n_in,
                              void* d_out, int out_size, void* d_ws, size_t ws_size,
                              hipStream_t stream) {
    const float* x = (const float*)d_in[0];
    const float* rots = (const float*)d_in[1];
    float* out = (float*)d_out;

    char* wsb = (char*)d_ws;
    float2* cs = (float2*)wsb;
    float* B0 = (float*)(wsb + 262144);
    float* B1 = B0 + (size_t)NSEG * MATE;

    k_sincos<<<128, 256, 0, stream>>>(rots, cs);
    k_build<<<NSEG * 4, 64, 0, stream>>>(cs, B0);
    k_combine<<<32 * 4, 256, 0, stream>>>(B0, B1, 0);
    k_combine<<<16 * 4, 256, 0, stream>>>(B1, B0, 0);
    k_combine<<<8 * 4, 256, 0, stream>>>(B0, B1, 0);
    k_combine<<<4 * 4, 256, 0, stream>>>(B1, B0, 0);
    k_combine<<<2 * 4, 256, 0, stream>>>(B0, B1, 0);
    k_combine<<<1 * 4, 256, 0, stream>>>(B1, B0, 1);
    k_gemm<<<1024, 256, 0, stream>>>(x, B0, out);
}

// Round 5
// 228.488 us; speedup vs baseline: 1.1595x; 1.1595x over previous
//
#include <hip/hip_runtime.h>
#include <hip/hip_bf16.h>
#include <math.h>

#define NDIM 256
#define NROT 32640          // C(256,2)
#define NSEG 64
#define SEGLEN 510          // 64 * 510 == 32640 exactly
#define MATE (NDIM * NDIM)  // elements per plane
#define NODEE (2 * MATE)    // node = hi plane + lo plane (bf16 each)

typedef __bf16 bf16x4_t __attribute__((ext_vector_type(4)));
typedef __bf16 bf16x8_t __attribute__((ext_vector_type(8)));
typedef float f32x4_t __attribute__((ext_vector_type(4)));

// ---------------------------------------------------------------------------
// K2: build 64 segment products (510 rotations each) applied to I, fp32 in
// LDS; sincos fused (each block computes its own 510 c/s into LDS).
// Output: bf16 hi/lo planes. even seg -> TRANSPOSED ([c][k]), odd -> plain.
// ---------------------------------------------------------------------------
__global__ __launch_bounds__(64, 1) void k_build(const float* __restrict__ rots,
                                                 __bf16* __restrict__ leaves) {
    __shared__ float tile[NDIM * 64];   // 64 KiB: 256 rows x 64 cols
    __shared__ float2 csl[SEGLEN + 8];
    const int t = threadIdx.x;          // 0..63
    const int seg = blockIdx.x >> 2;
    const int cg = blockIdx.x & 3;
    const int col = cg * 64 + t;

    // fused sincos: stage this segment's (c,s) into LDS
    const int kg0 = seg * SEGLEN;
    for (int u = t; u < SEGLEN; u += 64) {
        float th = rots[kg0 + u];
        float s, c;
        sincosf(th, &s, &c);
        csl[u] = make_float2(c, s);
    }
    for (int u = SEGLEN + t; u < SEGLEN + 8; u += 64) csl[u] = make_float2(1.f, 0.f);

    for (int r = 0; r < NDIM; r++) tile[r * 64 + t] = (r == col) ? 1.0f : 0.0f;
    // single wave: LDS ops execute in order, no barrier needed

    int k = 0;
    int i = 0, cum = 0;
    while (cum + (NDIM - 1 - i) <= kg0) { cum += NDIM - 1 - i; i++; }
    int j = i + 1 + (kg0 - cum);

    while (k < SEGLEN) {
        float ri = tile[i * 64 + t];
        const int len = min(NDIM - j, SEGLEN - k);
        const int jend = j + len;
        const int nb = len >> 3;

        if (nb > 0) {
            float2 cv[8]; float rj[8];
            #pragma unroll
            for (int u = 0; u < 8; u++) cv[u] = csl[k + u];
            #pragma unroll
            for (int u = 0; u < 8; u++) rj[u] = tile[(j + u) * 64 + t];
            for (int b = 0; b < nb - 1; b++) {
                float2 cvn[8]; float rjn[8];
                #pragma unroll
                for (int u = 0; u < 8; u++) cvn[u] = csl[k + 8 + u];
                #pragma unroll
                for (int u = 0; u < 8; u++) rjn[u] = tile[(j + 8 + u) * 64 + t];
                #pragma unroll
                for (int u = 0; u < 8; u++) {
                    float nri = fmaf(cv[u].x, ri, -(cv[u].y * rj[u]));
                    rj[u]     = fmaf(cv[u].y, ri,  cv[u].x * rj[u]);
                    ri = nri;
                }
                #pragma unroll
                for (int u = 0; u < 8; u++) tile[(j + u) * 64 + t] = rj[u];
                #pragma unroll
                for (int u = 0; u < 8; u++) { cv[u] = cvn[u]; rj[u] = rjn[u]; }
                j += 8; k += 8;
            }
            #pragma unroll
            for (int u = 0; u < 8; u++) {
                float nri = fmaf(cv[u].x, ri, -(cv[u].y * rj[u]));
                rj[u]     = fmaf(cv[u].y, ri,  cv[u].x * rj[u]);
                ri = nri;
            }
            #pragma unroll
            for (int u = 0; u < 8; u++) tile[(j + u) * 64 + t] = rj[u];
            j += 8; k += 8;
        }
        for (; j < jend; j++, k++) {
            float2 cv = csl[k];
            float rj = tile[j * 64 + t];
            float nri = fmaf(cv.x, ri, -(cv.y * rj));
            tile[j * 64 + t] = fmaf(cv.y, ri, cv.x * rj);
            ri = nri;
        }
        tile[i * 64 + t] = ri;
        if (j == NDIM) { i++; j = i + 1; }
    }

    __bf16* hi = leaves + (size_t)seg * NODEE;
    __bf16* lo = hi + MATE;
    if (seg & 1) {
        for (int r = 0; r < NDIM; r++) {
            float v = tile[r * 64 + t];
            __bf16 h = (__bf16)v;
            hi[r * NDIM + col] = h;
            lo[r * NDIM + col] = (__bf16)(v - (float)h);
        }
    } else {
        for (int r0 = 0; r0 < NDIM; r0 += 8) {
            bf16x8_t vh, vl;
            #pragma unroll
            for (int u = 0; u < 8; u++) {
                float v = tile[(r0 + u) * 64 + t];
                __bf16 h = (__bf16)v;
                vh[u] = h;
                vl[u] = (__bf16)(v - (float)h);
            }
            *(bf16x8_t*)&hi[(size_t)col * NDIM + r0] = vh;
            *(bf16x8_t*)&lo[(size_t)col * NDIM + r0] = vl;
        }
    }
}

// ---------------------------------------------------------------------------
// K3: one-shot tree combine. node[p] = child[2p+1] @ child[2p].
// Children as bf16 hi/lo planes; child[2p] transposed ([c][k]), child[2p+1]
// plain ([r][k]).  C ~= Bh@Ah + Bh@Al + Bl@Ah (fp32 acc).
// Block = 64x64 output over FULL K=256: stage 4 plane-tiles (132 KB LDS),
// ONE barrier, 96 MFMAs, store hi/lo (transposed if !final && p even).
// Grid = npairs*16, 256 threads (4 waves 2x2 of 32x32).
// ---------------------------------------------------------------------------
#define LDK 264   // padded LDS row (bf16); 528 B, 16B-aligned, bank-rotating
__global__ __launch_bounds__(256) void k_combine(const __bf16* __restrict__ src,
                                                 __bf16* __restrict__ dst,
                                                 int finalLevel) {
    __shared__ __bf16 planes[4][64 * LDK];   // Bhi, Blo, Ahi, Alo

    const int p = blockIdx.x >> 4;
    const int qd = blockIdx.x & 15;
    const int rbq = (qd >> 2) * 64;   // output row base (B rows)
    const int cbq = (qd & 3) * 64;    // output col base (A rows, transposed)
    const __bf16* A = src + (size_t)(2 * p) * NODEE;       // transposed child
    const __bf16* B = src + (size_t)(2 * p + 1) * NODEE;   // plain child
    __bf16* Chi = dst + (size_t)p * NODEE;
    __bf16* Clo = Chi + MATE;
    const bool storeT = (!finalLevel) && ((p & 1) == 0);

    const int t = threadIdx.x;
    const int wid = t >> 6, lane = t & 63;
    const int wr2 = (wid >> 1) * 32, wc2 = (wid & 1) * 32;
    const int lrow = lane & 15, kg = lane >> 4;

    const __bf16* plane_src[4] = {B, B + MATE, A, A + MATE};
    const int plane_row0[4] = {rbq, rbq, cbq, cbq};
    #pragma unroll
    for (int q = 0; q < 32; q++) {
        int g = q * 256 + t;
        int pl = g >> 11;            // 2048 16B-chunks per plane
        int c = g & 2047;
        int row = c >> 5, sg = c & 31;
        bf16x8_t v = *(const bf16x8_t*)&plane_src[pl][(size_t)(plane_row0[pl] + row) * NDIM + sg * 8];
        *(bf16x8_t*)&planes[pl][row * LDK + sg * 8] = v;
    }
    __syncthreads();

    f32x4_t acc[2][2] = {};
    #pragma unroll
    for (int kc = 0; kc < 8; kc++) {
        bf16x8_t afh[2], afl[2], bfh[2], bfl[2];
        #pragma unroll
        for (int mt = 0; mt < 2; mt++) {
            int r = (wr2 + mt * 16 + lrow) * LDK + kc * 32 + kg * 8;
            afh[mt] = *(const bf16x8_t*)&planes[0][r];
            afl[mt] = *(const bf16x8_t*)&planes[1][r];
        }
        #pragma unroll
        for (int nt = 0; nt < 2; nt++) {
            int r = (wc2 + nt * 16 + lrow) * LDK + kc * 32 + kg * 8;
            bfh[nt] = *(const bf16x8_t*)&planes[2][r];
            bfl[nt] = *(const bf16x8_t*)&planes[3][r];
        }
        #pragma unroll
        for (int mt = 0; mt < 2; mt++)
            #pragma unroll
            for (int nt = 0; nt < 2; nt++) {
                acc[mt][nt] = __builtin_amdgcn_mfma_f32_16x16x32_bf16(afh[mt], bfh[nt], acc[mt][nt], 0, 0, 0);
                acc[mt][nt] = __builtin_amdgcn_mfma_f32_16x16x32_bf16(afh[mt], bfl[nt], acc[mt][nt], 0, 0, 0);
                acc[mt][nt] = __builtin_amdgcn_mfma_f32_16x16x32_bf16(afl[mt], bfh[nt], acc[mt][nt], 0, 0, 0);
            }
    }

    // C/D: col = lane&15, row = (lane>>4)*4 + reg
    #pragma unroll
    for (int mt = 0; mt < 2; mt++)
        #pragma unroll
        for (int nt = 0; nt < 2; nt++) {
            int grow = rbq + wr2 + mt * 16 + kg * 4;
            int gcol = cbq + wc2 + nt * 16 + lrow;
            if (storeT) {
                bf16x4_t vh, vl;
                #pragma unroll
                for (int r = 0; r < 4; r++) {
                    float v = acc[mt][nt][r];
                    __bf16 h = (__bf16)v;
                    vh[r] = h;
                    vl[r] = (__bf16)(v - (float)h);
                }
                *(bf16x4_t*)&Chi[(size_t)gcol * NDIM + grow] = vh;
                *(bf16x4_t*)&Clo[(size_t)gcol * NDIM + grow] = vl;
            } else if (finalLevel) {
                #pragma unroll
                for (int r = 0; r < 4; r++)
                    Chi[(size_t)(grow + r) * NDIM + gcol] = (__bf16)acc[mt][nt][r];
            } else {
                #pragma unroll
                for (int r = 0; r < 4; r++) {
                    float v = acc[mt][nt][r];
                    __bf16 h = (__bf16)v;
                    Chi[(size_t)(grow + r) * NDIM + gcol] = h;
                    Clo[(size_t)(grow + r) * NDIM + gcol] = (__bf16)(v - (float)h);
                }
            }
        }
}

// ---------------------------------------------------------------------------
// K4: Y[b][c] = sum_k X[b][k] * Mhi[c][k]; Mhi bf16 row-major (root hi plane).
// BM=BN=128, BK=64 (4 iters), register prefetch of iter+1 global loads,
// 4 waves 2x2 of 64x64, LDS 36 KB.
// ---------------------------------------------------------------------------
#define LDA 72    // padded LDS row (bf16), 144 B
__global__ __launch_bounds__(256, 2) void k_gemm(const float* __restrict__ X,
                                                 const __bf16* __restrict__ Mhi,
                                                 float* __restrict__ Y) {
    __shared__ __bf16 As[128 * LDA];
    __shared__ __bf16 Bs[128 * LDA];
    const int bx = blockIdx.x;
    const int xcd = bx & 7;
    const int q = bx >> 3;
    const int bn = (q & 1) * 128;
    const int bm = (xcd + (q >> 1) * 8) * 128;
    const int t = threadIdx.x;
    const int wid = t >> 6;
    const int lane = t & 63;
    const int wr = (wid >> 1) * 64;
    const int wc = (wid & 1) * 64;
    const int lrow = lane & 15;
    const int kg = lane >> 4;

    f32x4_t acc[4][4] = {};

    f32x4_t ra[8];
    bf16x8_t rb[4];

    // prologue: load iter 0
    #pragma unroll
    for (int qq = 0; qq < 8; qq++) {
        int g = qq * 256 + t;
        ra[qq] = *(const f32x4_t*)&X[(size_t)(bm + (g >> 4)) * 256 + (g & 15) * 4];
    }
    #pragma unroll
    for (int qq = 0; qq < 4; qq++) {
        int g = qq * 256 + t;
        rb[qq] = *(const bf16x8_t*)&Mhi[(size_t)(bn + (g >> 3)) * 256 + (g & 7) * 8];
    }

    #pragma unroll
    for (int it = 0; it < 4; it++) {
        #pragma unroll
        for (int qq = 0; qq < 8; qq++) {
            int g = qq * 256 + t;
            f32x4_t v = ra[qq];
            bf16x4_t h = {(__bf16)v.x, (__bf16)v.y, (__bf16)v.z, (__bf16)v.w};
            *(bf16x4_t*)&As[(g >> 4) * LDA + (g & 15) * 4] = h;
        }
        #pragma unroll
        for (int qq = 0; qq < 4; qq++) {
            int g = qq * 256 + t;
            *(bf16x8_t*)&Bs[(g >> 3) * LDA + (g & 7) * 8] = rb[qq];
        }
        __syncthreads();

        if (it < 3) {
            int kc = (it + 1) * 64;
            #pragma unroll
            for (int qq = 0; qq < 8; qq++) {
                int g = qq * 256 + t;
                ra[qq] = *(const f32x4_t*)&X[(size_t)(bm + (g >> 4)) * 256 + kc + (g & 15) * 4];
            }
            #pragma unroll
            for (int qq = 0; qq < 4; qq++) {
                int g = qq * 256 + t;
                rb[qq] = *(const bf16x8_t*)&Mhi[(size_t)(bn + (g >> 3)) * 256 + kc + (g & 7) * 8];
            }
        }

        #pragma unroll
        for (int k2 = 0; k2 < 2; k2++) {
            bf16x8_t af[4], bfr[4];
            #pragma unroll
            for (int mt = 0; mt < 4; mt++)
                af[mt] = *(const bf16x8_t*)&As[(wr + mt * 16 + lrow) * LDA + k2 * 32 + kg * 8];
            #pragma unroll
            for (int nt = 0; nt < 4; nt++)
                bfr[nt] = *(const bf16x8_t*)&Bs[(wc + nt * 16 + lrow) * LDA + k2 * 32 + kg * 8];
            #pragma unroll
            for (int mt = 0; mt < 4; mt++)
                #pragma unroll
                for (int nt = 0; nt < 4; nt++)
                    acc[mt][nt] = __builtin_amdgcn_mfma_f32_16x16x32_bf16(af[mt], bfr[nt], acc[mt][nt], 0, 0, 0);
        }
        __syncthreads();
    }

    const int ocol = bn + wc + lrow;
    const int orow = bm + wr + kg * 4;
    #pragma unroll
    for (int mt = 0; mt < 4; mt++)
        #pragma unroll
        for (int nt = 0; nt < 4; nt++)
            #pragma unroll
            for (int r = 0; r < 4; r++)
                Y[(size_t)(orow + mt * 16 + r) * 256 + ocol + nt * 16] = acc[mt][nt][r];
}

// ---------------------------------------------------------------------------
// workspace: B0 = 64 nodes x 256 KB = 16 MB; B1 = 32 nodes x 256 KB = 8 MB.
// tree: B0(64) ->B1(32) ->B0(16) ->B1(8) ->B0(4) ->B1(2) ->B0(1=root, hi only)
// ---------------------------------------------------------------------------
extern "C" void kernel_launch(void* const* d_in, const int* in_sizes, int n_in,
                              void* d_out, int out_size, void* d_ws, size_t ws_size,
                              hipStream_t stream) {
    const float* x = (const float*)d_in[0];
    const float* rots = (const float*)d_in[1];
    float* out = (float*)d_out;

    __bf16* B0 = (__bf16*)d_ws;
    __bf16* B1 = B0 + (size_t)NSEG * NODEE;

    k_build<<<NSEG * 4, 64, 0, stream>>>(rots, B0);
    k_combine<<<32 * 16, 256, 0, stream>>>(B0, B1, 0);
    k_combine<<<16 * 16, 256, 0, stream>>>(B1, B0, 0);
    k_combine<<<8 * 16, 256, 0, stream>>>(B0, B1, 0);
    k_combine<<<4 * 16, 256, 0, stream>>>(B1, B0, 0);
    k_combine<<<2 * 16, 256, 0, stream>>>(B0, B1, 0);
    k_combine<<<1 * 16, 256, 0, stream>>>(B1, B0, 1);
    k_gemm<<<1024, 256, 0, stream>>>(x, B0, out);
}